// Round 5
// baseline (95.760 us; speedup 1.0000x reference)
//
#include <hip/hip_runtime.h>
#include <hip/hip_bf16.h>

#define NB 16
#define NC 256
#define NH 64
#define NW 64

typedef __attribute__((ext_vector_type(8))) short bf16x8;
typedef __attribute__((ext_vector_type(4))) float f32x4;

__device__ __forceinline__ unsigned short f2bf(float f) {
    union { float f; unsigned int u; } v; v.f = f;
    unsigned int u = v.u;
    u += 0x7fffu + ((u >> 16) & 1u);   // round-to-nearest-even
    return (unsigned short)(u >> 16);
}

// 16B-slot XOR swizzle; conflict-free for our write patterns, <=2-way reads
__device__ __forceinline__ int swzT(int row, int col) {   // [rows][256] tile
    return row * 256 + ((((col >> 3) ^ (row & 7) ^ ((row >> 3) & 7)) << 3) | (col & 7));
}
__device__ __forceinline__ int swzS(int row, int col) {   // [rows][64] tile
    return row * 64 + ((((col >> 3) ^ (row & 7) ^ ((row >> 3) & 7)) << 3) | (col & 7));
}

// ---- prep: G = Wq^T Wk (bf16), u = Wk^T bq, v = Wq^T bk (bf16), s = bq.bk ----
__global__ void prep_g(const float* __restrict__ wq, const float* __restrict__ wk,
                       const float* __restrict__ bq, const float* __restrict__ bk,
                       unsigned short* __restrict__ wsb) {
    int c2 = threadIdx.x;
    int c1 = blockIdx.x;
    if (c1 < 256) {
        float acc = 0.f;
        #pragma unroll 4
        for (int o = 0; o < 256; ++o)
            acc += wq[o * 256 + c1] * wk[o * 256 + c2];
        wsb[c1 * 256 + c2] = f2bf(acc);
    } else {
        float u = 0.f, v = 0.f;
        #pragma unroll 4
        for (int o = 0; o < 256; ++o) {
            u += bq[o] * wk[o * 256 + c2];
            v += bk[o] * wq[o * 256 + c2];
        }
        wsb[131072 + c2] = f2bf(u);
        wsb[131328 + c2] = f2bf(v);
        if (c2 == 0) {
            float s = 0.f;
            for (int o = 0; o < 256; ++o) s += bq[o] * bk[o];
            *(float*)(wsb + 131584) = s;
        }
    }
}

__global__ void prep_wv(const float* __restrict__ wv, unsigned short* __restrict__ wsb) {
    int i = blockIdx.x * 256 + threadIdx.x;   // 16384 float4s total
    float4 t = ((const float4*)wv)[i];
    ushort4 u = { f2bf(t.x), f2bf(t.y), f2bf(t.z), f2bf(t.w) };
    ((ushort4*)(wsb + 65536))[i] = u;
}

// LDS: AT [64 w][256 c] @0 | TT [64 x][256 c1] / Vs [256 c][64 x] @16384 |
//      ATT [64 w][64 x] @32768 | uAvA[128] f32.  Total 74,240 B -> 2 blocks/CU.
__launch_bounds__(512, 4)
__global__ void mha_fused(const float* __restrict__ a,
                          const unsigned short* __restrict__ wsb,
                          const float* __restrict__ bv,
                          float* __restrict__ out) {
    __shared__ __align__(16) unsigned short smem[36864];
    __shared__ __align__(16) float uAvA[128];
    unsigned short* AT  = smem;
    unsigned short* TT  = smem + 16384;
    unsigned short* Vs  = smem + 16384;   // aliases TT (dead after attn)
    unsigned short* ATT = smem + 32768;

    const unsigned short* Gb  = wsb;
    const unsigned short* Wvb = wsb + 65536;
    const unsigned short* ub  = wsb + 131072;
    const unsigned short* vbv = wsb + 131328;

    const int tid = threadIdx.x;
    const int b = blockIdx.x >> 6;
    const int h = blockIdx.x & 63;
    const float* aB = a + (size_t)b * (NC * NH * NW) + h * NW;

    // ---- P1: global [c][w] fp32 -> reg 4x4 transpose -> AT[w][c] bf16 ----
    #pragma unroll
    for (int half = 0; half < 2; ++half) {
        int mt = tid + half * 512;
        int c0 = (mt >> 4) << 2;
        int w0 = (mt & 15) << 2;
        float4 r0 = *(const float4*)(aB + (size_t)(c0 + 0) * 4096 + w0);
        float4 r1 = *(const float4*)(aB + (size_t)(c0 + 1) * 4096 + w0);
        float4 r2 = *(const float4*)(aB + (size_t)(c0 + 2) * 4096 + w0);
        float4 r3 = *(const float4*)(aB + (size_t)(c0 + 3) * 4096 + w0);
        const float* f0 = (const float*)&r0;
        const float* f1 = (const float*)&r1;
        const float* f2 = (const float*)&r2;
        const float* f3 = (const float*)&r3;
        #pragma unroll
        for (int j = 0; j < 4; ++j) {
            ushort4 u = { f2bf(f0[j]), f2bf(f1[j]), f2bf(f2[j]), f2bf(f3[j]) };
            *(ushort4*)(AT + swzT(w0 + j, c0)) = u;
        }
    }
    __syncthreads();

    const int wv_ = tid >> 6;
    const int lane = tid & 63;
    const int l15 = lane & 15;
    const int g = lane >> 4;

    // ---- P2: T = G*A  (D rows c1, cols x) + broadcast-MFMA uA/vA ----
    {
        f32x4 acc[2][4];
        #pragma unroll
        for (int mi = 0; mi < 2; ++mi)
            #pragma unroll
            for (int n = 0; n < 4; ++n) acc[mi][n] = { 0.f, 0.f, 0.f, 0.f };

        const bool is_u = (wv_ < 4);
        const int uvtile = wv_ & 3;
        const int uvrow = uvtile * 16 + l15;
        const float sval = *(const float*)(wsb + 131584);
        f32x4 accu;
        #pragma unroll
        for (int r = 0; r < 4; ++r) accu[r] = is_u ? sval : 0.f;
        const unsigned short* uvp = is_u ? ub : vbv;

        #pragma unroll
        for (int kk = 0; kk < 8; ++kk) {
            bf16x8 gf[2], atf[4];
            #pragma unroll
            for (int mi = 0; mi < 2; ++mi)
                gf[mi] = *(const bf16x8*)(Gb + (wv_ * 32 + mi * 16 + l15) * 256 + kk * 32 + g * 8);
            #pragma unroll
            for (int n = 0; n < 4; ++n)
                atf[n] = *(const bf16x8*)(AT + swzT(n * 16 + l15, kk * 32 + g * 8));
            #pragma unroll
            for (int mi = 0; mi < 2; ++mi)
                #pragma unroll
                for (int n = 0; n < 4; ++n)
                    acc[mi][n] = __builtin_amdgcn_mfma_f32_16x16x32_bf16(gf[mi], atf[n], acc[mi][n], 0, 0, 0);
            bf16x8 uvf  = *(const bf16x8*)(uvp + kk * 32 + g * 8);
            bf16x8 uvbf = *(const bf16x8*)(AT + swzT(uvrow, kk * 32 + g * 8));
            accu = __builtin_amdgcn_mfma_f32_16x16x32_bf16(uvf, uvbf, accu, 0, 0, 0);
        }
        // TT[x][c1] epilogue: ushort4 along c1 (= D rows)
        #pragma unroll
        for (int mi = 0; mi < 2; ++mi) {
            int c1_0 = wv_ * 32 + mi * 16 + g * 4;
            #pragma unroll
            for (int n = 0; n < 4; ++n) {
                ushort4 u = { f2bf(acc[mi][n][0]), f2bf(acc[mi][n][1]),
                              f2bf(acc[mi][n][2]), f2bf(acc[mi][n][3]) };
                *(ushort4*)(TT + swzT(n * 16 + l15, c1_0)) = u;
            }
        }
        if (g == 0)
            uAvA[(is_u ? 0 : 64) + uvrow] = accu[0];
    }
    __syncthreads();

    // ---- P3: attn = A^T T + rank-1 (D rows x, cols w) ----
    const int wt3 = wv_ >> 1;
    const int xb3 = (wv_ & 1) * 2;
    {
        f32x4 acc3[2] = { { 0, 0, 0, 0 }, { 0, 0, 0, 0 } };
        #pragma unroll
        for (int kk = 0; kk < 8; ++kk) {
            bf16x8 awf = *(const bf16x8*)(AT + swzT(wt3 * 16 + l15, kk * 32 + g * 8));
            #pragma unroll
            for (int j = 0; j < 2; ++j) {
                bf16x8 txf = *(const bf16x8*)(TT + swzT((xb3 + j) * 16 + l15, kk * 32 + g * 8));
                acc3[j] = __builtin_amdgcn_mfma_f32_16x16x32_bf16(txf, awf, acc3[j], 0, 0, 0);
            }
        }
        const int w = wt3 * 16 + l15;
        const float vAw = uAvA[64 + w];
        #pragma unroll
        for (int j = 0; j < 2; ++j) {
            int x0 = (xb3 + j) * 16 + g * 4;
            float4 uq = *(const float4*)&uAvA[x0];
            const float* uqa = (const float*)&uq;
            ushort4 u = { f2bf(acc3[j][0] + uqa[0] + vAw), f2bf(acc3[j][1] + uqa[1] + vAw),
                          f2bf(acc3[j][2] + uqa[2] + vAw), f2bf(acc3[j][3] + uqa[3] + vAw) };
            *(ushort4*)(ATT + swzS(w, x0)) = u;
        }
    }
    __syncthreads();   // TT reads done -> Vs may overwrite; ATT visible later

    // ---- P4: Vs = Wv*A + bv  (D rows x, cols c) ----
    {
        f32x4 acc[2][4];
        #pragma unroll
        for (int mi = 0; mi < 2; ++mi) {
            float bvl = bv[wv_ * 32 + mi * 16 + l15];
            #pragma unroll
            for (int n = 0; n < 4; ++n) acc[mi][n] = { bvl, bvl, bvl, bvl };
        }
        #pragma unroll
        for (int kk = 0; kk < 8; ++kk) {
            bf16x8 atx[4], wvf[2];
            #pragma unroll
            for (int n = 0; n < 4; ++n)
                atx[n] = *(const bf16x8*)(AT + swzT(n * 16 + l15, kk * 32 + g * 8));
            #pragma unroll
            for (int mi = 0; mi < 2; ++mi)
                wvf[mi] = *(const bf16x8*)(Wvb + (wv_ * 32 + mi * 16 + l15) * 256 + kk * 32 + g * 8);
            #pragma unroll
            for (int mi = 0; mi < 2; ++mi)
                #pragma unroll
                for (int n = 0; n < 4; ++n)
                    acc[mi][n] = __builtin_amdgcn_mfma_f32_16x16x32_bf16(atx[n], wvf[mi], acc[mi][n], 0, 0, 0);
        }
        #pragma unroll
        for (int mi = 0; mi < 2; ++mi) {
            int c = wv_ * 32 + mi * 16 + l15;
            #pragma unroll
            for (int n = 0; n < 4; ++n) {
                ushort4 u = { f2bf(acc[mi][n][0]), f2bf(acc[mi][n][1]),
                              f2bf(acc[mi][n][2]), f2bf(acc[mi][n][3]) };
                *(ushort4*)(Vs + swzS(c, n * 16 + g * 4)) = u;
            }
        }
    }
    __syncthreads();

    // ---- P5: O = ATT x Vs (D rows w, cols c), fp32 residual epilogue ----
    {
        f32x4 acc[2][4];
        #pragma unroll
        for (int mi = 0; mi < 2; ++mi)
            #pragma unroll
            for (int n = 0; n < 4; ++n) acc[mi][n] = { 0.f, 0.f, 0.f, 0.f };
        #pragma unroll
        for (int kk = 0; kk < 2; ++kk) {
            bf16x8 attf[4], vsf[2];
            #pragma unroll
            for (int n = 0; n < 4; ++n)
                attf[n] = *(const bf16x8*)(ATT + swzS(n * 16 + l15, kk * 32 + g * 8));
            #pragma unroll
            for (int mi = 0; mi < 2; ++mi)
                vsf[mi] = *(const bf16x8*)(Vs + swzS(wv_ * 32 + mi * 16 + l15, kk * 32 + g * 8));
            #pragma unroll
            for (int mi = 0; mi < 2; ++mi)
                #pragma unroll
                for (int n = 0; n < 4; ++n)
                    acc[mi][n] = __builtin_amdgcn_mfma_f32_16x16x32_bf16(attf[n], vsf[mi], acc[mi][n], 0, 0, 0);
        }
        float* outB = out + (size_t)b * (NC * NH * NW) + h * NW;
        #pragma unroll
        for (int mi = 0; mi < 2; ++mi) {
            int c = wv_ * 32 + mi * 16 + l15;
            const float* ain = aB + (size_t)c * 4096;
            float* po = outB + (size_t)c * 4096;
            #pragma unroll
            for (int n = 0; n < 4; ++n) {
                int w0 = n * 16 + g * 4;
                float4 res = *(const float4*)(ain + w0);
                float4 o4;
                o4.x = res.x + acc[mi][n][0];
                o4.y = res.y + acc[mi][n][1];
                o4.z = res.z + acc[mi][n][2];
                o4.w = res.w + acc[mi][n][3];
                *(float4*)(po + w0) = o4;
            }
        }
    }
}

extern "C" void kernel_launch(void* const* d_in, const int* in_sizes, int n_in,
                              void* d_out, int out_size, void* d_ws, size_t ws_size,
                              hipStream_t stream) {
    (void)in_sizes; (void)n_in; (void)out_size; (void)ws_size;
    const float* a  = (const float*)d_in[0];
    const float* wq = (const float*)d_in[1];
    const float* bq = (const float*)d_in[2];
    const float* wk = (const float*)d_in[3];
    const float* bk = (const float*)d_in[4];
    const float* wv = (const float*)d_in[5];
    const float* bv = (const float*)d_in[6];
    float* out = (float*)d_out;
    unsigned short* wsb = (unsigned short*)d_ws;  // G | Wv_bf16 | u | v | s

    prep_g<<<dim3(257), dim3(256), 0, stream>>>(wq, wk, bq, bk, wsb);
    prep_wv<<<dim3(64), dim3(256), 0, stream>>>(wv, wsb);
    mha_fused<<<dim3(NB * NH), dim3(512), 0, stream>>>(a, wsb, bv, out);
}